// Round 5
// baseline (68.117 us; speedup 1.0000x reference)
//
#include <hip/hip_runtime.h>
#include <hip/hip_bf16.h>
#include <climits>

// Problem constants: B=8, C=8, H=512, W=512
#define HWSZ 262144      // H*W
#define CHWSZ 2097152    // C*H*W

typedef short short8 __attribute__((ext_vector_type(8)));   // 8 bf16 (4 VGPRs)
typedef float f32x4 __attribute__((ext_vector_type(4)));    // MFMA accumulator
typedef float f4 __attribute__((ext_vector_type(4)));       // component-indexable float4
typedef unsigned short u16x8 __attribute__((ext_vector_type(8)));  // 16B label chunk

// ---------------- argmax, register loads, NON-TEMPORAL ----------------
// R1-R4: four structurally different read patterns all pin at ~45us (~3.0 TB/s
// effective), including L3-warm replays -> limiter is common to HBM and L3 service:
// the L2 miss/allocate/evict path (128 MB streams through 4 MB/XCD L2, every line
// a miss+allocate+evict). NT loads set the nt policy bit -> no L2 allocation on
// miss, relieving the tag/victim machinery. Single-variable change vs R2.
__global__ __launch_bounds__(256) void hd_argmax(const float* __restrict__ logits,
                                                 const float* __restrict__ target,
                                                 ushort* __restrict__ lxb,
                                                 ushort* __restrict__ tyb) {
    int t = blockIdx.x * 256 + threadIdx.x;   // 0 .. 256K-1
    int p = t << 3;                           // pixel index (8 px per thread)
    int b = p >> 18;                          // / (H*W)
    int off = p & (HWSZ - 1);

    const f4* L = (const f4*)(logits + (size_t)b * CHWSZ + off);
    const f4* T = (const f4*)(target + (size_t)b * CHWSZ + off);

    // ---- logits ----
    f4 v[16];
#pragma unroll
    for (int c = 0; c < 8; ++c) {
        v[2 * c]     = __builtin_nontemporal_load(&L[c * (HWSZ / 4)]);
        v[2 * c + 1] = __builtin_nontemporal_load(&L[c * (HWSZ / 4) + 1]);
    }
    u16x8 ub;
#pragma unroll
    for (int half = 0; half < 2; ++half) {
#pragma unroll
        for (int j = 0; j < 4; ++j) {
            float bv = v[half][j];
            int bi = 0;
#pragma unroll
            for (int c = 1; c < 8; ++c) {
                float x = v[2 * c + half][j];
                bool g = x > bv;            // strict >: first-max, matches jnp.argmax
                bv = g ? x : bv;
                bi = g ? c : bi;
            }
            ub[half * 4 + j] = (ushort)(__float_as_uint((float)bi) >> 16);  // exact bf16 0..7
        }
    }
    __builtin_nontemporal_store(ub, (u16x8*)(lxb + p));

    // ---- target ----
    f4 w[16];
#pragma unroll
    for (int c = 0; c < 8; ++c) {
        w[2 * c]     = __builtin_nontemporal_load(&T[c * (HWSZ / 4)]);
        w[2 * c + 1] = __builtin_nontemporal_load(&T[c * (HWSZ / 4) + 1]);
    }
    u16x8 wb;
#pragma unroll
    for (int half = 0; half < 2; ++half) {
#pragma unroll
        for (int j = 0; j < 4; ++j) {
            float bv = w[half][j];
            int bi = 0;
#pragma unroll
            for (int c = 1; c < 8; ++c) {
                float x = w[2 * c + half][j];
                bool g = x > bv;
                bv = g ? x : bv;
                bi = g ? c : bi;
            }
            wb[half * 4 + j] = (ushort)(__float_as_uint((float)bi) >> 16);
        }
    }
    __builtin_nontemporal_store(wb, (u16x8*)(tyb + p));
}

// ---------------- row norms + min-buffer init: one wave per row, no atomics ----------------
__global__ __launch_bounds__(256) void hd_norms(const ushort* __restrict__ lxb,
                                                const ushort* __restrict__ tyb,
                                                float* __restrict__ x2,
                                                float* __restrict__ y2,
                                                int* __restrict__ rowmin,
                                                int* __restrict__ colmin) {
    int gid = blockIdx.x * 256 + threadIdx.x;
    if (gid < 4096) {            // fused init (runs before hd_dist on the same stream)
        rowmin[gid] = INT_MAX;
        colmin[gid] = INT_MAX;
    }
    int wid = blockIdx.x * 4 + (threadIdx.x >> 6);   // 0..8191
    int l = threadIdx.x & 63;
    const ushort* src = (wid < 4096) ? (lxb + wid * 512) : (tyb + (wid - 4096) * 512);
    u16x8 u = *(const u16x8*)(src + l * 8);
    float s = 0.0f;
#pragma unroll
    for (int j = 0; j < 8; ++j) {
        float f = __uint_as_float((unsigned)u[j] << 16);
        s += f * f;
    }
#pragma unroll
    for (int o = 32; o > 0; o >>= 1) s += __shfl_xor(s, o, 64);
    if (l == 0) {
        if (wid < 4096) x2[wid] = s; else y2[wid - 4096] = s;
    }
}

// ---------------- 64x64-tile MFMA distance kernel ----------------
// Grid (64, 8). 4 waves/block, wave (wr,wc) owns a 32x32 quadrant as 2x2 16x16x32 frags.
// Fragments load straight from global (label maps are 512KB/batch -> L2-hot).
// d2 = x2[i] + y2[j] - 2*<x_i,y_j> (exact integer), reduced via shfl + atomicMin.
__global__ __launch_bounds__(256) void hd_dist(const ushort* __restrict__ lxb,
                                               const ushort* __restrict__ tyb,
                                               const float* __restrict__ x2,
                                               const float* __restrict__ y2,
                                               int* __restrict__ rowmin,
                                               int* __restrict__ colmin) {
    int b = blockIdx.y;
    int ti = blockIdx.x >> 3, tj = blockIdx.x & 7;
    int tid = threadIdx.x;
    int l = tid & 63;
    int wv = tid >> 6;
    int wr = wv >> 1, wc = wv & 1;
    int lr = l & 15, lg = l >> 4;

    const ushort* X = lxb + b * HWSZ + (ti * 64 + wr * 32 + lr) * 512 + lg * 8;
    const ushort* Y = tyb + b * HWSZ + (tj * 64 + wc * 32 + lr) * 512 + lg * 8;

    f32x4 acc00 = {0.f, 0.f, 0.f, 0.f};
    f32x4 acc01 = {0.f, 0.f, 0.f, 0.f};
    f32x4 acc10 = {0.f, 0.f, 0.f, 0.f};
    f32x4 acc11 = {0.f, 0.f, 0.f, 0.f};

#pragma unroll 4
    for (int kk = 0; kk < 512; kk += 32) {
        short8 a0 = *(const short8*)(X + kk);
        short8 a1 = *(const short8*)(X + 8192 + kk);   // +16 rows
        short8 b0 = *(const short8*)(Y + kk);
        short8 b1 = *(const short8*)(Y + 8192 + kk);
        acc00 = __builtin_amdgcn_mfma_f32_16x16x32_bf16(a0, b0, acc00, 0, 0, 0);
        acc01 = __builtin_amdgcn_mfma_f32_16x16x32_bf16(a0, b1, acc01, 0, 0, 0);
        acc10 = __builtin_amdgcn_mfma_f32_16x16x32_bf16(a1, b0, acc10, 0, 0, 0);
        acc11 = __builtin_amdgcn_mfma_f32_16x16x32_bf16(a1, b1, acc11, 0, 0, 0);
    }

    int rb = (b << 9) + ti * 64 + wr * 32;
    int cb = (b << 9) + tj * 64 + wc * 32;
    float x2v0[4], x2v1[4];
#pragma unroll
    for (int r = 0; r < 4; ++r) {
        x2v0[r] = x2[rb + lg * 4 + r];
        x2v1[r] = x2[rb + 16 + lg * 4 + r];
    }
    float y2v0 = y2[cb + lr];
    float y2v1 = y2[cb + 16 + lr];

    int d2[2][2][4];
#pragma unroll
    for (int r = 0; r < 4; ++r) {
        d2[0][0][r] = (int)(fmaxf(fmaf(-2.0f, acc00[r], x2v0[r] + y2v0), 0.0f) + 0.5f);
        d2[0][1][r] = (int)(fmaxf(fmaf(-2.0f, acc01[r], x2v0[r] + y2v1), 0.0f) + 0.5f);
        d2[1][0][r] = (int)(fmaxf(fmaf(-2.0f, acc10[r], x2v1[r] + y2v0), 0.0f) + 0.5f);
        d2[1][1][r] = (int)(fmaxf(fmaf(-2.0f, acc11[r], x2v1[r] + y2v1), 0.0f) + 0.5f);
    }

    // row mins: row r held by 16 lanes sharing lg (C layout: col = l&15)
#pragma unroll
    for (int fi = 0; fi < 2; ++fi) {
#pragma unroll
        for (int r = 0; r < 4; ++r) {
            int m = min(d2[fi][0][r], d2[fi][1][r]);
            m = min(m, __shfl_xor(m, 1, 64));
            m = min(m, __shfl_xor(m, 2, 64));
            m = min(m, __shfl_xor(m, 4, 64));
            m = min(m, __shfl_xor(m, 8, 64));
            if (lr == 0) atomicMin(&rowmin[rb + fi * 16 + lg * 4 + r], m);
        }
    }
    // col mins
#pragma unroll
    for (int fj = 0; fj < 2; ++fj) {
        int m;
        if (fj == 0) {
            m = min(min(min(d2[0][0][0], d2[0][0][1]), min(d2[0][0][2], d2[0][0][3])),
                    min(min(d2[1][0][0], d2[1][0][1]), min(d2[1][0][2], d2[1][0][3])));
        } else {
            m = min(min(min(d2[0][1][0], d2[0][1][1]), min(d2[0][1][2], d2[0][1][3])),
                    min(min(d2[1][1][0], d2[1][1][1]), min(d2[1][1][2], d2[1][1][3])));
        }
        m = min(m, __shfl_xor(m, 16, 64));
        m = min(m, __shfl_xor(m, 32, 64));
        if (lg == 0) atomicMin(&colmin[cb + fj * 16 + lr], m);
    }
}

// ---------------- final: per-batch max over (rowmin ∪ colmin), sqrt, mean ----------------
__global__ __launch_bounds__(512) void hd_final(const int* __restrict__ rowmin,
                                                const int* __restrict__ colmin,
                                                float* __restrict__ out) {
    int w = threadIdx.x >> 6, l = threadIdx.x & 63;   // wave w = batch w
    int m = 0;
#pragma unroll
    for (int j = 0; j < 512; j += 64) {
        m = max(m, rowmin[(w << 9) + j + l]);
        m = max(m, colmin[(w << 9) + j + l]);
    }
#pragma unroll
    for (int s = 32; s > 0; s >>= 1) m = max(m, __shfl_xor(m, s, 64));
    __shared__ float hd[8];
    if (l == 0) hd[w] = sqrtf((float)m);
    __syncthreads();
    if (threadIdx.x == 0) {
        float s = 0.0f;
#pragma unroll
        for (int i = 0; i < 8; ++i) s += hd[i];
        out[0] = s * 0.125f;
    }
}

extern "C" void kernel_launch(void* const* d_in, const int* in_sizes, int n_in,
                              void* d_out, int out_size, void* d_ws, size_t ws_size,
                              hipStream_t stream) {
    (void)in_sizes; (void)n_in; (void)out_size; (void)ws_size;
    const float* logits = (const float*)d_in[0];
    const float* target = (const float*)d_in[1];

    char* ws = (char*)d_ws;
    ushort* lxb = (ushort*)ws;                          // 2M bf16 = 4 MB
    ushort* tyb = (ushort*)(ws + (4u << 20));           // 4 MB
    float* x2   = (float*)(ws + (8u << 20));            // 4096 f32
    float* y2   = x2 + 4096;                            // 4096 f32
    int* rowmin = (int*)(y2 + 4096);                    // 4096 i32
    int* colmin = rowmin + 4096;                        // 4096 i32
    float* out  = (float*)d_out;

    hipLaunchKernelGGL(hd_argmax, dim3(1024),  dim3(256), 0, stream, logits, target, lxb, tyb);
    hipLaunchKernelGGL(hd_norms,  dim3(2048),  dim3(256), 0, stream, lxb, tyb, x2, y2, rowmin, colmin);
    hipLaunchKernelGGL(hd_dist,   dim3(64, 8), dim3(256), 0, stream, lxb, tyb, x2, y2, rowmin, colmin);
    hipLaunchKernelGGL(hd_final,  dim3(1),     dim3(512), 0, stream, rowmin, colmin, out);
}

// Round 6
// 67.741 us; speedup vs baseline: 1.0056x; 1.0056x over previous
//
#include <hip/hip_runtime.h>
#include <hip/hip_bf16.h>
#include <climits>

// Problem constants: B=8, C=8, H=512, W=512
#define HWSZ 262144      // H*W
#define CHWSZ 2097152    // C*H*W

typedef short short8 __attribute__((ext_vector_type(8)));   // 8 bf16 (4 VGPRs)
typedef float f32x4 __attribute__((ext_vector_type(4)));    // MFMA accumulator
typedef float f4 __attribute__((ext_vector_type(4)));       // component-indexable float4
typedef unsigned short u16x8 __attribute__((ext_vector_type(8)));  // 16B label chunk

// ---------------- argmax: NT loads (keep, R5: 45.4->40.6us), PLAIN stores (revert) ----
// R1-R5 established: read service caps at ~3.2-3.4 TB/s regardless of structure
// (scalar chain / batched reg / DMA->LDS / scattered blocks / NT), including
// L3-warm replays -> XCD inbound read-path limit, not HBM/latency/channel issue.
// 128 MB irreducible read -> ~39us floor; NT loads get us there. Labels MUST stay
// cacheable: hd_dist re-reads them ~8x from L2/L3 (NT stores cost +20us in R5).
__global__ __launch_bounds__(256) void hd_argmax(const float* __restrict__ logits,
                                                 const float* __restrict__ target,
                                                 ushort* __restrict__ lxb,
                                                 ushort* __restrict__ tyb) {
    int t = blockIdx.x * 256 + threadIdx.x;   // 0 .. 256K-1
    int p = t << 3;                           // pixel index (8 px per thread)
    int b = p >> 18;                          // / (H*W)
    int off = p & (HWSZ - 1);

    const f4* L = (const f4*)(logits + (size_t)b * CHWSZ + off);
    const f4* T = (const f4*)(target + (size_t)b * CHWSZ + off);

    // ---- logits ----
    f4 v[16];
#pragma unroll
    for (int c = 0; c < 8; ++c) {
        v[2 * c]     = __builtin_nontemporal_load(&L[c * (HWSZ / 4)]);
        v[2 * c + 1] = __builtin_nontemporal_load(&L[c * (HWSZ / 4) + 1]);
    }
    u16x8 ub;
#pragma unroll
    for (int half = 0; half < 2; ++half) {
#pragma unroll
        for (int j = 0; j < 4; ++j) {
            float bv = v[half][j];
            int bi = 0;
#pragma unroll
            for (int c = 1; c < 8; ++c) {
                float x = v[2 * c + half][j];
                bool g = x > bv;            // strict >: first-max, matches jnp.argmax
                bv = g ? x : bv;
                bi = g ? c : bi;
            }
            ub[half * 4 + j] = (ushort)(__float_as_uint((float)bi) >> 16);  // exact bf16 0..7
        }
    }
    *(u16x8*)(lxb + p) = ub;   // plain store: labels must stay L2/L3-resident

    // ---- target ----
    f4 w[16];
#pragma unroll
    for (int c = 0; c < 8; ++c) {
        w[2 * c]     = __builtin_nontemporal_load(&T[c * (HWSZ / 4)]);
        w[2 * c + 1] = __builtin_nontemporal_load(&T[c * (HWSZ / 4) + 1]);
    }
    u16x8 wb;
#pragma unroll
    for (int half = 0; half < 2; ++half) {
#pragma unroll
        for (int j = 0; j < 4; ++j) {
            float bv = w[half][j];
            int bi = 0;
#pragma unroll
            for (int c = 1; c < 8; ++c) {
                float x = w[2 * c + half][j];
                bool g = x > bv;
                bv = g ? x : bv;
                bi = g ? c : bi;
            }
            wb[half * 4 + j] = (ushort)(__float_as_uint((float)bi) >> 16);
        }
    }
    *(u16x8*)(tyb + p) = wb;
}

// ---------------- row norms + min-buffer init: one wave per row, no atomics ----------------
__global__ __launch_bounds__(256) void hd_norms(const ushort* __restrict__ lxb,
                                                const ushort* __restrict__ tyb,
                                                float* __restrict__ x2,
                                                float* __restrict__ y2,
                                                int* __restrict__ rowmin,
                                                int* __restrict__ colmin) {
    int gid = blockIdx.x * 256 + threadIdx.x;
    if (gid < 4096) {            // fused init (runs before hd_dist on the same stream)
        rowmin[gid] = INT_MAX;
        colmin[gid] = INT_MAX;
    }
    int wid = blockIdx.x * 4 + (threadIdx.x >> 6);   // 0..8191
    int l = threadIdx.x & 63;
    const ushort* src = (wid < 4096) ? (lxb + wid * 512) : (tyb + (wid - 4096) * 512);
    u16x8 u = *(const u16x8*)(src + l * 8);
    float s = 0.0f;
#pragma unroll
    for (int j = 0; j < 8; ++j) {
        float f = __uint_as_float((unsigned)u[j] << 16);
        s += f * f;
    }
#pragma unroll
    for (int o = 32; o > 0; o >>= 1) s += __shfl_xor(s, o, 64);
    if (l == 0) {
        if (wid < 4096) x2[wid] = s; else y2[wid - 4096] = s;
    }
}

// ---------------- 64x64-tile MFMA distance kernel ----------------
// Grid (64, 8). 4 waves/block, wave (wr,wc) owns a 32x32 quadrant as 2x2 16x16x32 frags.
// Fragments load straight from global (label maps are 512KB/batch -> L2-hot).
// d2 = x2[i] + y2[j] - 2*<x_i,y_j> (exact integer), reduced via shfl + atomicMin.
__global__ __launch_bounds__(256) void hd_dist(const ushort* __restrict__ lxb,
                                               const ushort* __restrict__ tyb,
                                               const float* __restrict__ x2,
                                               const float* __restrict__ y2,
                                               int* __restrict__ rowmin,
                                               int* __restrict__ colmin) {
    int b = blockIdx.y;
    int ti = blockIdx.x >> 3, tj = blockIdx.x & 7;
    int tid = threadIdx.x;
    int l = tid & 63;
    int wv = tid >> 6;
    int wr = wv >> 1, wc = wv & 1;
    int lr = l & 15, lg = l >> 4;

    const ushort* X = lxb + b * HWSZ + (ti * 64 + wr * 32 + lr) * 512 + lg * 8;
    const ushort* Y = tyb + b * HWSZ + (tj * 64 + wc * 32 + lr) * 512 + lg * 8;

    f32x4 acc00 = {0.f, 0.f, 0.f, 0.f};
    f32x4 acc01 = {0.f, 0.f, 0.f, 0.f};
    f32x4 acc10 = {0.f, 0.f, 0.f, 0.f};
    f32x4 acc11 = {0.f, 0.f, 0.f, 0.f};

#pragma unroll 4
    for (int kk = 0; kk < 512; kk += 32) {
        short8 a0 = *(const short8*)(X + kk);
        short8 a1 = *(const short8*)(X + 8192 + kk);   // +16 rows
        short8 b0 = *(const short8*)(Y + kk);
        short8 b1 = *(const short8*)(Y + 8192 + kk);
        acc00 = __builtin_amdgcn_mfma_f32_16x16x32_bf16(a0, b0, acc00, 0, 0, 0);
        acc01 = __builtin_amdgcn_mfma_f32_16x16x32_bf16(a0, b1, acc01, 0, 0, 0);
        acc10 = __builtin_amdgcn_mfma_f32_16x16x32_bf16(a1, b0, acc10, 0, 0, 0);
        acc11 = __builtin_amdgcn_mfma_f32_16x16x32_bf16(a1, b1, acc11, 0, 0, 0);
    }

    int rb = (b << 9) + ti * 64 + wr * 32;
    int cb = (b << 9) + tj * 64 + wc * 32;
    float x2v0[4], x2v1[4];
#pragma unroll
    for (int r = 0; r < 4; ++r) {
        x2v0[r] = x2[rb + lg * 4 + r];
        x2v1[r] = x2[rb + 16 + lg * 4 + r];
    }
    float y2v0 = y2[cb + lr];
    float y2v1 = y2[cb + 16 + lr];

    int d2[2][2][4];
#pragma unroll
    for (int r = 0; r < 4; ++r) {
        d2[0][0][r] = (int)(fmaxf(fmaf(-2.0f, acc00[r], x2v0[r] + y2v0), 0.0f) + 0.5f);
        d2[0][1][r] = (int)(fmaxf(fmaf(-2.0f, acc01[r], x2v0[r] + y2v1), 0.0f) + 0.5f);
        d2[1][0][r] = (int)(fmaxf(fmaf(-2.0f, acc10[r], x2v1[r] + y2v0), 0.0f) + 0.5f);
        d2[1][1][r] = (int)(fmaxf(fmaf(-2.0f, acc11[r], x2v1[r] + y2v1), 0.0f) + 0.5f);
    }

    // row mins: row r held by 16 lanes sharing lg (C layout: col = l&15)
#pragma unroll
    for (int fi = 0; fi < 2; ++fi) {
#pragma unroll
        for (int r = 0; r < 4; ++r) {
            int m = min(d2[fi][0][r], d2[fi][1][r]);
            m = min(m, __shfl_xor(m, 1, 64));
            m = min(m, __shfl_xor(m, 2, 64));
            m = min(m, __shfl_xor(m, 4, 64));
            m = min(m, __shfl_xor(m, 8, 64));
            if (lr == 0) atomicMin(&rowmin[rb + fi * 16 + lg * 4 + r], m);
        }
    }
    // col mins
#pragma unroll
    for (int fj = 0; fj < 2; ++fj) {
        int m;
        if (fj == 0) {
            m = min(min(min(d2[0][0][0], d2[0][0][1]), min(d2[0][0][2], d2[0][0][3])),
                    min(min(d2[1][0][0], d2[1][0][1]), min(d2[1][0][2], d2[1][0][3])));
        } else {
            m = min(min(min(d2[0][1][0], d2[0][1][1]), min(d2[0][1][2], d2[0][1][3])),
                    min(min(d2[1][1][0], d2[1][1][1]), min(d2[1][1][2], d2[1][1][3])));
        }
        m = min(m, __shfl_xor(m, 16, 64));
        m = min(m, __shfl_xor(m, 32, 64));
        if (lg == 0) atomicMin(&colmin[cb + fj * 16 + lr], m);
    }
}

// ---------------- final: per-batch max over (rowmin ∪ colmin), sqrt, mean ----------------
__global__ __launch_bounds__(512) void hd_final(const int* __restrict__ rowmin,
                                                const int* __restrict__ colmin,
                                                float* __restrict__ out) {
    int w = threadIdx.x >> 6, l = threadIdx.x & 63;   // wave w = batch w
    int m = 0;
#pragma unroll
    for (int j = 0; j < 512; j += 64) {
        m = max(m, rowmin[(w << 9) + j + l]);
        m = max(m, colmin[(w << 9) + j + l]);
    }
#pragma unroll
    for (int s = 32; s > 0; s >>= 1) m = max(m, __shfl_xor(m, s, 64));
    __shared__ float hd[8];
    if (l == 0) hd[w] = sqrtf((float)m);
    __syncthreads();
    if (threadIdx.x == 0) {
        float s = 0.0f;
#pragma unroll
        for (int i = 0; i < 8; ++i) s += hd[i];
        out[0] = s * 0.125f;
    }
}

extern "C" void kernel_launch(void* const* d_in, const int* in_sizes, int n_in,
                              void* d_out, int out_size, void* d_ws, size_t ws_size,
                              hipStream_t stream) {
    (void)in_sizes; (void)n_in; (void)out_size; (void)ws_size;
    const float* logits = (const float*)d_in[0];
    const float* target = (const float*)d_in[1];

    char* ws = (char*)d_ws;
    ushort* lxb = (ushort*)ws;                          // 2M bf16 = 4 MB
    ushort* tyb = (ushort*)(ws + (4u << 20));           // 4 MB
    float* x2   = (float*)(ws + (8u << 20));            // 4096 f32
    float* y2   = x2 + 4096;                            // 4096 f32
    int* rowmin = (int*)(y2 + 4096);                    // 4096 i32
    int* colmin = rowmin + 4096;                        // 4096 i32
    float* out  = (float*)d_out;

    hipLaunchKernelGGL(hd_argmax, dim3(1024),  dim3(256), 0, stream, logits, target, lxb, tyb);
    hipLaunchKernelGGL(hd_norms,  dim3(2048),  dim3(256), 0, stream, lxb, tyb, x2, y2, rowmin, colmin);
    hipLaunchKernelGGL(hd_dist,   dim3(64, 8), dim3(256), 0, stream, lxb, tyb, x2, y2, rowmin, colmin);
    hipLaunchKernelGGL(hd_final,  dim3(1),     dim3(512), 0, stream, rowmin, colmin, out);
}

// Round 7
// 66.207 us; speedup vs baseline: 1.0289x; 1.0232x over previous
//
#include <hip/hip_runtime.h>
#include <hip/hip_bf16.h>
#include <climits>

// Problem constants: B=8, C=8, H=512, W=512
#define HWSZ 262144      // H*W
#define CHWSZ 2097152    // C*H*W

typedef short short8 __attribute__((ext_vector_type(8)));   // 8 bf16 (4 VGPRs)
typedef float f32x4 __attribute__((ext_vector_type(4)));    // MFMA accumulator
typedef float f4 __attribute__((ext_vector_type(4)));       // component-indexable float4
typedef unsigned short u16x8 __attribute__((ext_vector_type(8)));  // 16B label chunk

// ---------------- argmax: NT loads; fused row-norms (wave==row, no atomics) + min-init --
// R1-R6: read service caps at ~2.9-3.4 TB/s for any structure (incl. L3-warm) ->
// XCD read-path limit; 128 MB irreducible -> ~40us floor, NT loads reach it.
// 8 px/thread => one wave covers exactly one 512-px image row => per-row sums are a
// wave shfl-reduce + ONE direct store (no atomics). Blocks 0..15 init rowmin/colmin.
__global__ __launch_bounds__(256) void hd_argmax(const float* __restrict__ logits,
                                                 const float* __restrict__ target,
                                                 ushort* __restrict__ lxb,
                                                 ushort* __restrict__ tyb,
                                                 float* __restrict__ x2,
                                                 float* __restrict__ y2,
                                                 int* __restrict__ rowmin,
                                                 int* __restrict__ colmin) {
    int gid = blockIdx.x * 256 + threadIdx.x;
    if (gid < 4096) {            // fused init (dist runs later on the same stream)
        rowmin[gid] = INT_MAX;
        colmin[gid] = INT_MAX;
    }
    int t = gid;                              // 0 .. 256K-1
    int p = t << 3;                           // pixel index (8 px per thread)
    int b = p >> 18;                          // / (H*W)
    int off = p & (HWSZ - 1);
    int l = threadIdx.x & 63;
    int row = p >> 9;                         // global row 0..4095 (same for whole wave)

    const f4* L = (const f4*)(logits + (size_t)b * CHWSZ + off);
    const f4* T = (const f4*)(target + (size_t)b * CHWSZ + off);

    // ---- logits ----
    {
        f4 v[16];
#pragma unroll
        for (int c = 0; c < 8; ++c) {
            v[2 * c]     = __builtin_nontemporal_load(&L[c * (HWSZ / 4)]);
            v[2 * c + 1] = __builtin_nontemporal_load(&L[c * (HWSZ / 4) + 1]);
        }
        u16x8 ub;
        int s = 0;
#pragma unroll
        for (int half = 0; half < 2; ++half) {
#pragma unroll
            for (int j = 0; j < 4; ++j) {
                float bv = v[half][j];
                int bi = 0;
#pragma unroll
                for (int c = 1; c < 8; ++c) {
                    float x = v[2 * c + half][j];
                    bool g = x > bv;            // strict >: first-max, matches jnp.argmax
                    bv = g ? x : bv;
                    bi = g ? c : bi;
                }
                ub[half * 4 + j] = (ushort)(__float_as_uint((float)bi) >> 16);  // exact bf16
                s += bi * bi;
            }
        }
        *(u16x8*)(lxb + p) = ub;   // plain store: labels feed hd_dist via L2/L3
#pragma unroll
        for (int o = 32; o > 0; o >>= 1) s += __shfl_xor(s, o, 64);
        if (l == 0) x2[row] = (float)s;
    }
    // ---- target ----
    {
        f4 w[16];
#pragma unroll
        for (int c = 0; c < 8; ++c) {
            w[2 * c]     = __builtin_nontemporal_load(&T[c * (HWSZ / 4)]);
            w[2 * c + 1] = __builtin_nontemporal_load(&T[c * (HWSZ / 4) + 1]);
        }
        u16x8 wb;
        int s = 0;
#pragma unroll
        for (int half = 0; half < 2; ++half) {
#pragma unroll
            for (int j = 0; j < 4; ++j) {
                float bv = w[half][j];
                int bi = 0;
#pragma unroll
                for (int c = 1; c < 8; ++c) {
                    float x = w[2 * c + half][j];
                    bool g = x > bv;
                    bv = g ? x : bv;
                    bi = g ? c : bi;
                }
                wb[half * 4 + j] = (ushort)(__float_as_uint((float)bi) >> 16);
                s += bi * bi;
            }
        }
        *(u16x8*)(tyb + p) = wb;
#pragma unroll
        for (int o = 32; o > 0; o >>= 1) s += __shfl_xor(s, o, 64);
        if (l == 0) y2[row] = (float)s;
    }
}

// ---------------- 64x64-tile MFMA distance kernel, XCD-region swizzle ----------------
// Round-robin block->XCD means XCD = (blockIdx.x + 64*b) % 8 = blockIdx.x % 8.
// Old mapping t=ti*8+tj gave each XCD one column-band: X rows had ZERO within-XCD
// reuse -> every X fragment served from L3/fabric (~3 TB/s) -> ~25us tail (R5/R6).
// New mapping: XCD x owns a 2-row x 4-col tile region -> unique L3 bytes per XCD
// per batch = 384 KB (was ~4.5 MB); everything else hits local L2 (~34 TB/s).
__global__ __launch_bounds__(256) void hd_dist(const ushort* __restrict__ lxb,
                                               const ushort* __restrict__ tyb,
                                               const float* __restrict__ x2,
                                               const float* __restrict__ y2,
                                               int* __restrict__ rowmin,
                                               int* __restrict__ colmin) {
    int b = blockIdx.y;
    int x = blockIdx.x & 7, k = blockIdx.x >> 3;            // x: XCD slot, k: local idx
    int ti = 2 * (x & 3) + (k & 1);                         // 2-row band
    int tj = 4 * (x >> 2) + (k >> 1);                       // 4-col band
    int tid = threadIdx.x;
    int l = tid & 63;
    int wv = tid >> 6;
    int wr = wv >> 1, wc = wv & 1;
    int lr = l & 15, lg = l >> 4;

    const ushort* X = lxb + b * HWSZ + (ti * 64 + wr * 32 + lr) * 512 + lg * 8;
    const ushort* Y = tyb + b * HWSZ + (tj * 64 + wc * 32 + lr) * 512 + lg * 8;

    f32x4 acc00 = {0.f, 0.f, 0.f, 0.f};
    f32x4 acc01 = {0.f, 0.f, 0.f, 0.f};
    f32x4 acc10 = {0.f, 0.f, 0.f, 0.f};
    f32x4 acc11 = {0.f, 0.f, 0.f, 0.f};

#pragma unroll 4
    for (int kk = 0; kk < 512; kk += 32) {
        short8 a0 = *(const short8*)(X + kk);
        short8 a1 = *(const short8*)(X + 8192 + kk);   // +16 rows
        short8 b0 = *(const short8*)(Y + kk);
        short8 b1 = *(const short8*)(Y + 8192 + kk);
        acc00 = __builtin_amdgcn_mfma_f32_16x16x32_bf16(a0, b0, acc00, 0, 0, 0);
        acc01 = __builtin_amdgcn_mfma_f32_16x16x32_bf16(a0, b1, acc01, 0, 0, 0);
        acc10 = __builtin_amdgcn_mfma_f32_16x16x32_bf16(a1, b0, acc10, 0, 0, 0);
        acc11 = __builtin_amdgcn_mfma_f32_16x16x32_bf16(a1, b1, acc11, 0, 0, 0);
    }

    int rb = (b << 9) + ti * 64 + wr * 32;
    int cb = (b << 9) + tj * 64 + wc * 32;
    float x2v0[4], x2v1[4];
#pragma unroll
    for (int r = 0; r < 4; ++r) {
        x2v0[r] = x2[rb + lg * 4 + r];
        x2v1[r] = x2[rb + 16 + lg * 4 + r];
    }
    float y2v0 = y2[cb + lr];
    float y2v1 = y2[cb + 16 + lr];

    int d2[2][2][4];
#pragma unroll
    for (int r = 0; r < 4; ++r) {
        d2[0][0][r] = (int)(fmaxf(fmaf(-2.0f, acc00[r], x2v0[r] + y2v0), 0.0f) + 0.5f);
        d2[0][1][r] = (int)(fmaxf(fmaf(-2.0f, acc01[r], x2v0[r] + y2v1), 0.0f) + 0.5f);
        d2[1][0][r] = (int)(fmaxf(fmaf(-2.0f, acc10[r], x2v1[r] + y2v0), 0.0f) + 0.5f);
        d2[1][1][r] = (int)(fmaxf(fmaf(-2.0f, acc11[r], x2v1[r] + y2v1), 0.0f) + 0.5f);
    }

    // row mins: row r held by 16 lanes sharing lg (C layout: col = l&15)
#pragma unroll
    for (int fi = 0; fi < 2; ++fi) {
#pragma unroll
        for (int r = 0; r < 4; ++r) {
            int m = min(d2[fi][0][r], d2[fi][1][r]);
            m = min(m, __shfl_xor(m, 1, 64));
            m = min(m, __shfl_xor(m, 2, 64));
            m = min(m, __shfl_xor(m, 4, 64));
            m = min(m, __shfl_xor(m, 8, 64));
            if (lr == 0) atomicMin(&rowmin[rb + fi * 16 + lg * 4 + r], m);
        }
    }
    // col mins
#pragma unroll
    for (int fj = 0; fj < 2; ++fj) {
        int m;
        if (fj == 0) {
            m = min(min(min(d2[0][0][0], d2[0][0][1]), min(d2[0][0][2], d2[0][0][3])),
                    min(min(d2[1][0][0], d2[1][0][1]), min(d2[1][0][2], d2[1][0][3])));
        } else {
            m = min(min(min(d2[0][1][0], d2[0][1][1]), min(d2[0][1][2], d2[0][1][3])),
                    min(min(d2[1][1][0], d2[1][1][1]), min(d2[1][1][2], d2[1][1][3])));
        }
        m = min(m, __shfl_xor(m, 16, 64));
        m = min(m, __shfl_xor(m, 32, 64));
        if (lg == 0) atomicMin(&colmin[cb + fj * 16 + lr], m);
    }
}

// ---------------- final: per-batch max over (rowmin ∪ colmin), sqrt, mean ----------------
__global__ __launch_bounds__(512) void hd_final(const int* __restrict__ rowmin,
                                                const int* __restrict__ colmin,
                                                float* __restrict__ out) {
    int w = threadIdx.x >> 6, l = threadIdx.x & 63;   // wave w = batch w
    int m = 0;
#pragma unroll
    for (int j = 0; j < 512; j += 64) {
        m = max(m, rowmin[(w << 9) + j + l]);
        m = max(m, colmin[(w << 9) + j + l]);
    }
#pragma unroll
    for (int s = 32; s > 0; s >>= 1) m = max(m, __shfl_xor(m, s, 64));
    __shared__ float hd[8];
    if (l == 0) hd[w] = sqrtf((float)m);
    __syncthreads();
    if (threadIdx.x == 0) {
        float s = 0.0f;
#pragma unroll
        for (int i = 0; i < 8; ++i) s += hd[i];
        out[0] = s * 0.125f;
    }
}

extern "C" void kernel_launch(void* const* d_in, const int* in_sizes, int n_in,
                              void* d_out, int out_size, void* d_ws, size_t ws_size,
                              hipStream_t stream) {
    (void)in_sizes; (void)n_in; (void)out_size; (void)ws_size;
    const float* logits = (const float*)d_in[0];
    const float* target = (const float*)d_in[1];

    char* ws = (char*)d_ws;
    ushort* lxb = (ushort*)ws;                          // 2M bf16 = 4 MB
    ushort* tyb = (ushort*)(ws + (4u << 20));           // 4 MB
    float* x2   = (float*)(ws + (8u << 20));            // 4096 f32
    float* y2   = x2 + 4096;                            // 4096 f32
    int* rowmin = (int*)(y2 + 4096);                    // 4096 i32
    int* colmin = rowmin + 4096;                        // 4096 i32
    float* out  = (float*)d_out;

    hipLaunchKernelGGL(hd_argmax, dim3(1024),  dim3(256), 0, stream,
                       logits, target, lxb, tyb, x2, y2, rowmin, colmin);
    hipLaunchKernelGGL(hd_dist,   dim3(64, 8), dim3(256), 0, stream,
                       lxb, tyb, x2, y2, rowmin, colmin);
    hipLaunchKernelGGL(hd_final,  dim3(1),     dim3(512), 0, stream, rowmin, colmin, out);
}

// Round 8
// 50.326 us; speedup vs baseline: 1.3535x; 1.3156x over previous
//
#include <hip/hip_runtime.h>
#include <hip/hip_bf16.h>
#include <climits>

// Problem constants: B=8, C=8, H=512, W=512
#define HWSZ 262144      // H*W
#define CHWSZ 2097152    // C*H*W

typedef short short8 __attribute__((ext_vector_type(8)));   // 8 bf16 (4 VGPRs)
typedef float f32x4 __attribute__((ext_vector_type(4)));    // MFMA accumulator
typedef float f4 __attribute__((ext_vector_type(4)));       // component-indexable float4
typedef unsigned short u16x8 __attribute__((ext_vector_type(8)));  // 16B label chunk

// ---------------- argmax: CACHED loads (NT reverted), fused row-norms + min-init ------
// Empirical ledger (R1-R7): read service from beyond local L2 caps at ~3.2 TB/s
// (warm L3 replays identical to cold) -> argmax floor ~44-45us cached / ~40us NT.
// But NT input loads cost +21us in the downstream kernels (tail 3->25us, 3/3
// reproductions, insensitive to store policy/swizzle/fusion). Net: revert NT.
__global__ __launch_bounds__(256) void hd_argmax(const float* __restrict__ logits,
                                                 const float* __restrict__ target,
                                                 ushort* __restrict__ lxb,
                                                 ushort* __restrict__ tyb,
                                                 float* __restrict__ x2,
                                                 float* __restrict__ y2,
                                                 int* __restrict__ rowmin,
                                                 int* __restrict__ colmin) {
    int gid = blockIdx.x * 256 + threadIdx.x;
    if (gid < 4096) {            // fused init (dist runs later on the same stream)
        rowmin[gid] = INT_MAX;
        colmin[gid] = INT_MAX;
    }
    int t = gid;                              // 0 .. 256K-1
    int p = t << 3;                           // pixel index (8 px per thread)
    int b = p >> 18;                          // / (H*W)
    int off = p & (HWSZ - 1);
    int l = threadIdx.x & 63;
    int row = p >> 9;                         // global row 0..4095 (same for whole wave)

    const f4* L = (const f4*)(logits + (size_t)b * CHWSZ + off);
    const f4* T = (const f4*)(target + (size_t)b * CHWSZ + off);

    // ---- logits ----
    {
        f4 v[16];
#pragma unroll
        for (int c = 0; c < 8; ++c) {
            v[2 * c]     = L[c * (HWSZ / 4)];
            v[2 * c + 1] = L[c * (HWSZ / 4) + 1];
        }
        u16x8 ub;
        int s = 0;
#pragma unroll
        for (int half = 0; half < 2; ++half) {
#pragma unroll
            for (int j = 0; j < 4; ++j) {
                float bv = v[half][j];
                int bi = 0;
#pragma unroll
                for (int c = 1; c < 8; ++c) {
                    float x = v[2 * c + half][j];
                    bool g = x > bv;            // strict >: first-max, matches jnp.argmax
                    bv = g ? x : bv;
                    bi = g ? c : bi;
                }
                ub[half * 4 + j] = (ushort)(__float_as_uint((float)bi) >> 16);  // exact bf16
                s += bi * bi;
            }
        }
        *(u16x8*)(lxb + p) = ub;   // plain store: labels feed hd_dist via L2/L3
#pragma unroll
        for (int o = 32; o > 0; o >>= 1) s += __shfl_xor(s, o, 64);
        if (l == 0) x2[row] = (float)s;
    }
    // ---- target ----
    {
        f4 w[16];
#pragma unroll
        for (int c = 0; c < 8; ++c) {
            w[2 * c]     = T[c * (HWSZ / 4)];
            w[2 * c + 1] = T[c * (HWSZ / 4) + 1];
        }
        u16x8 wb;
        int s = 0;
#pragma unroll
        for (int half = 0; half < 2; ++half) {
#pragma unroll
            for (int j = 0; j < 4; ++j) {
                float bv = w[half][j];
                int bi = 0;
#pragma unroll
                for (int c = 1; c < 8; ++c) {
                    float x = w[2 * c + half][j];
                    bool g = x > bv;
                    bv = g ? x : bv;
                    bi = g ? c : bi;
                }
                wb[half * 4 + j] = (ushort)(__float_as_uint((float)bi) >> 16);
                s += bi * bi;
            }
        }
        *(u16x8*)(tyb + p) = wb;
#pragma unroll
        for (int o = 32; o > 0; o >>= 1) s += __shfl_xor(s, o, 64);
        if (l == 0) y2[row] = (float)s;
    }
}

// ---------------- 64x64-tile MFMA distance kernel, batch-per-XCD ----------------
// B=8=XCD count. Flat grid 512; batch = blockIdx.x % 8 -> under round-robin
// dispatch all 64 blocks of a batch share one XCD: unique beyond-L2 label bytes
// = 1 MB/XCD (first touch), the other ~56 MB of tile re-reads hit local L2.
// d2 = x2[i] + y2[j] - 2*<x_i,y_j> (exact integer), reduced via shfl + atomicMin.
__global__ __launch_bounds__(256) void hd_dist(const ushort* __restrict__ lxb,
                                               const ushort* __restrict__ tyb,
                                               const float* __restrict__ x2,
                                               const float* __restrict__ y2,
                                               int* __restrict__ rowmin,
                                               int* __restrict__ colmin) {
    int b = blockIdx.x & 7;                   // batch == XCD slot
    int k = blockIdx.x >> 3;                  // 0..63 tile index within batch
    int ti = k >> 3, tj = k & 7;
    int tid = threadIdx.x;
    int l = tid & 63;
    int wv = tid >> 6;
    int wr = wv >> 1, wc = wv & 1;
    int lr = l & 15, lg = l >> 4;

    const ushort* X = lxb + b * HWSZ + (ti * 64 + wr * 32 + lr) * 512 + lg * 8;
    const ushort* Y = tyb + b * HWSZ + (tj * 64 + wc * 32 + lr) * 512 + lg * 8;

    f32x4 acc00 = {0.f, 0.f, 0.f, 0.f};
    f32x4 acc01 = {0.f, 0.f, 0.f, 0.f};
    f32x4 acc10 = {0.f, 0.f, 0.f, 0.f};
    f32x4 acc11 = {0.f, 0.f, 0.f, 0.f};

#pragma unroll 4
    for (int kk = 0; kk < 512; kk += 32) {
        short8 a0 = *(const short8*)(X + kk);
        short8 a1 = *(const short8*)(X + 8192 + kk);   // +16 rows
        short8 b0 = *(const short8*)(Y + kk);
        short8 b1 = *(const short8*)(Y + 8192 + kk);
        acc00 = __builtin_amdgcn_mfma_f32_16x16x32_bf16(a0, b0, acc00, 0, 0, 0);
        acc01 = __builtin_amdgcn_mfma_f32_16x16x32_bf16(a0, b1, acc01, 0, 0, 0);
        acc10 = __builtin_amdgcn_mfma_f32_16x16x32_bf16(a1, b0, acc10, 0, 0, 0);
        acc11 = __builtin_amdgcn_mfma_f32_16x16x32_bf16(a1, b1, acc11, 0, 0, 0);
    }

    int rb = (b << 9) + ti * 64 + wr * 32;
    int cb = (b << 9) + tj * 64 + wc * 32;
    float x2v0[4], x2v1[4];
#pragma unroll
    for (int r = 0; r < 4; ++r) {
        x2v0[r] = x2[rb + lg * 4 + r];
        x2v1[r] = x2[rb + 16 + lg * 4 + r];
    }
    float y2v0 = y2[cb + lr];
    float y2v1 = y2[cb + 16 + lr];

    int d2[2][2][4];
#pragma unroll
    for (int r = 0; r < 4; ++r) {
        d2[0][0][r] = (int)(fmaxf(fmaf(-2.0f, acc00[r], x2v0[r] + y2v0), 0.0f) + 0.5f);
        d2[0][1][r] = (int)(fmaxf(fmaf(-2.0f, acc01[r], x2v0[r] + y2v1), 0.0f) + 0.5f);
        d2[1][0][r] = (int)(fmaxf(fmaf(-2.0f, acc10[r], x2v1[r] + y2v0), 0.0f) + 0.5f);
        d2[1][1][r] = (int)(fmaxf(fmaf(-2.0f, acc11[r], x2v1[r] + y2v1), 0.0f) + 0.5f);
    }

    // row mins: row r held by 16 lanes sharing lg (C layout: col = l&15)
#pragma unroll
    for (int fi = 0; fi < 2; ++fi) {
#pragma unroll
        for (int r = 0; r < 4; ++r) {
            int m = min(d2[fi][0][r], d2[fi][1][r]);
            m = min(m, __shfl_xor(m, 1, 64));
            m = min(m, __shfl_xor(m, 2, 64));
            m = min(m, __shfl_xor(m, 4, 64));
            m = min(m, __shfl_xor(m, 8, 64));
            if (lr == 0) atomicMin(&rowmin[rb + fi * 16 + lg * 4 + r], m);
        }
    }
    // col mins
#pragma unroll
    for (int fj = 0; fj < 2; ++fj) {
        int m;
        if (fj == 0) {
            m = min(min(min(d2[0][0][0], d2[0][0][1]), min(d2[0][0][2], d2[0][0][3])),
                    min(min(d2[1][0][0], d2[1][0][1]), min(d2[1][0][2], d2[1][0][3])));
        } else {
            m = min(min(min(d2[0][1][0], d2[0][1][1]), min(d2[0][1][2], d2[0][1][3])),
                    min(min(d2[1][1][0], d2[1][1][1]), min(d2[1][1][2], d2[1][1][3])));
        }
        m = min(m, __shfl_xor(m, 16, 64));
        m = min(m, __shfl_xor(m, 32, 64));
        if (lg == 0) atomicMin(&colmin[cb + fj * 16 + lr], m);
    }
}

// ---------------- final: per-batch max over (rowmin ∪ colmin), sqrt, mean ----------------
__global__ __launch_bounds__(512) void hd_final(const int* __restrict__ rowmin,
                                                const int* __restrict__ colmin,
                                                float* __restrict__ out) {
    int w = threadIdx.x >> 6, l = threadIdx.x & 63;   // wave w = batch w
    int m = 0;
#pragma unroll
    for (int j = 0; j < 512; j += 64) {
        m = max(m, rowmin[(w << 9) + j + l]);
        m = max(m, colmin[(w << 9) + j + l]);
    }
#pragma unroll
    for (int s = 32; s > 0; s >>= 1) m = max(m, __shfl_xor(m, s, 64));
    __shared__ float hd[8];
    if (l == 0) hd[w] = sqrtf((float)m);
    __syncthreads();
    if (threadIdx.x == 0) {
        float s = 0.0f;
#pragma unroll
        for (int i = 0; i < 8; ++i) s += hd[i];
        out[0] = s * 0.125f;
    }
}

extern "C" void kernel_launch(void* const* d_in, const int* in_sizes, int n_in,
                              void* d_out, int out_size, void* d_ws, size_t ws_size,
                              hipStream_t stream) {
    (void)in_sizes; (void)n_in; (void)out_size; (void)ws_size;
    const float* logits = (const float*)d_in[0];
    const float* target = (const float*)d_in[1];

    char* ws = (char*)d_ws;
    ushort* lxb = (ushort*)ws;                          // 2M bf16 = 4 MB
    ushort* tyb = (ushort*)(ws + (4u << 20));           // 4 MB
    float* x2   = (float*)(ws + (8u << 20));            // 4096 f32
    float* y2   = x2 + 4096;                            // 4096 f32
    int* rowmin = (int*)(y2 + 4096);                    // 4096 i32
    int* colmin = rowmin + 4096;                        // 4096 i32
    float* out  = (float*)d_out;

    hipLaunchKernelGGL(hd_argmax, dim3(1024), dim3(256), 0, stream,
                       logits, target, lxb, tyb, x2, y2, rowmin, colmin);
    hipLaunchKernelGGL(hd_dist,   dim3(512),  dim3(256), 0, stream,
                       lxb, tyb, x2, y2, rowmin, colmin);
    hipLaunchKernelGGL(hd_final,  dim3(1),    dim3(512), 0, stream, rowmin, colmin, out);
}